// Round 2
// baseline (1781.368 us; speedup 1.0000x reference)
//
#include <hip/hip_runtime.h>

// Fused grouped conv: x(128,6,256,256) fp32, VALID 5x5, out(128,16,252,252).
// oc 0-5  = CH3 groups (3 in-ch each), oc 6-14 = CH4 groups (4 in-ch),
// oc 15   = CH6 (all 6 ch). Each input channel feeds exactly 10 outputs.
//
// Consumer tables (hardcoded from reference CH3/CH4/CH6):
// kind: 0 -> w3 (oc=g),  1 -> w4 (oc=6+g),  2 -> w6 (oc=15, pos=c)
namespace {
constexpr int CKIND[6][10] = {
  {0,0,0, 1,1,1,1,1,1, 2},
  {0,0,0, 1,1,1,1,1,1, 2},
  {0,0,0, 1,1,1,1,1,1, 2},
  {0,0,0, 1,1,1,1,1,1, 2},
  {0,0,0, 1,1,1,1,1,1, 2},
  {0,0,0, 1,1,1,1,1,1, 2},
};
constexpr int CG[6][10] = {
  {0,4,5, 0,3,4,5,6,8, 0},
  {0,1,5, 0,1,4,5,6,7, 0},
  {0,1,2, 0,1,2,5,7,8, 0},
  {1,2,3, 0,1,2,3,6,8, 0},
  {2,3,4, 1,2,3,4,6,7, 0},
  {3,4,5, 2,3,4,5,7,8, 0},
};
constexpr int CPOS[6][10] = {
  {0,0,0, 0,0,0,0,0,0, 0},
  {1,0,1, 1,0,1,1,1,0, 1},
  {2,1,0, 2,1,0,2,1,1, 2},
  {2,1,0, 3,2,1,1,2,2, 3},
  {2,1,1, 3,2,2,2,3,2, 4},
  {2,2,2, 3,3,3,3,3,3, 5},
};
} // namespace

#define TW 64
#define TH 16
#define IW 68   // TW+4
#define IH 20   // TH+4
#define LDS_CH (IH*IW)  // 1360 floats per channel

// launch_bounds(256, 1): VGPR budget 512/wave. History:
//   (256,4) -> 64 VGPR, massive spill, 16.6 GB HBM, 5400 us
//   (256,2) -> 128 VGPR, residual spill (~1.5 GB excess WRITE_SIZE), 1164 us
// Live set is ~170 regs (acc[16][4]=64 + r[8] + weight/addr temps); give the
// allocator room. Occupancy drops to 1-2 blocks/CU but the 64 independent
// accumulator chains provide all the ILP needed to keep the VALU pipe busy.
__global__ __launch_bounds__(256, 1)
void conv_fused(const float* __restrict__ x,
                const float* __restrict__ w3, const float* __restrict__ b3,
                const float* __restrict__ w4, const float* __restrict__ b4,
                const float* __restrict__ w6, const float* __restrict__ b6,
                float* __restrict__ out)
{
  __shared__ __align__(16) float smem[6 * LDS_CH];
  const int tid = threadIdx.x;
  const int bx = blockIdx.x;       // 0..3   x-tiles
  const int by = blockIdx.y;       // 0..15  y-tiles
  const int b  = blockIdx.z;       // batch
  const int x0 = bx * TW;
  const int y0 = by * TH;

  // ---- stage 6 x 20 x 68 input tile into LDS (float4, zero-fill OOB) ----
  const float* xb = x + (size_t)b * 6 * 256 * 256;
  for (int i = tid; i < 6 * IH * 17; i += 256) {
    int row = i / 17;            // 0..119
    int v   = i - row * 17;      // 0..16 (float4 index within row)
    int c   = row / IH;
    int y   = row - c * IH;
    int gy  = y0 + y;
    int gx  = x0 + v * 4;
    float4 val = make_float4(0.f, 0.f, 0.f, 0.f);
    if (gy < 256 && gx < 256)
      val = *(const float4*)(xb + ((size_t)c * 256 + gy) * 256 + gx);
    *(float4*)(&smem[c * LDS_CH + y * IW + v * 4]) = val;
  }
  __syncthreads();

  const int tx = (tid & 15) * 4;   // output col within tile: 0,4,...,60
  const int ty = tid >> 4;         // output row within tile: 0..15

  // ---- accumulators: 16 oc x 4 px, init with bias ----
  float acc[16][4];
  #pragma unroll
  for (int oc = 0; oc < 16; ++oc) {
    float bv = (oc < 6) ? b3[oc] : (oc < 15 ? b4[oc - 6] : b6[0]);
    #pragma unroll
    for (int p = 0; p < 4; ++p) acc[oc][p] = bv;
  }

  // ---- main loop: fully unrolled, sparse pattern compile-time ----
  #pragma unroll
  for (int c = 0; c < 6; ++c) {
    #pragma unroll
    for (int ky = 0; ky < 5; ++ky) {
      const float* rp = &smem[c * LDS_CH + (ty + ky) * IW + tx];
      float4 ra = *(const float4*)rp;
      float4 rb = *(const float4*)(rp + 4);
      float r[8] = {ra.x, ra.y, ra.z, ra.w, rb.x, rb.y, rb.z, rb.w};
      #pragma unroll
      for (int kx = 0; kx < 5; ++kx) {
        const int tap = ky * 5 + kx;
        #pragma unroll
        for (int j = 0; j < 10; ++j) {
          const int kind = CKIND[c][j];
          const int g    = CG[c][j];
          const int pos  = CPOS[c][j];
          float wv;
          if (kind == 0)      wv = w3[(g * 3 + pos) * 25 + tap];
          else if (kind == 1) wv = w4[(g * 4 + pos) * 25 + tap];
          else                wv = w6[pos * 25 + tap];
          const int oc = (kind == 0) ? g : ((kind == 1) ? 6 + g : 15);
          #pragma unroll
          for (int p = 0; p < 4; ++p)
            acc[oc][p] = fmaf(r[kx + p], wv, acc[oc][p]);
        }
      }
    }
  }

  // ---- store: float4 per oc, guarded (252 % 4 == 0 so vec4 guard is exact) ----
  const int oy = y0 + ty;
  const int ox = x0 + tx;
  if (oy < 252 && ox < 252) {
    float* ob = out + (((size_t)b * 16) * 252 + oy) * 252 + ox;
    #pragma unroll
    for (int oc = 0; oc < 16; ++oc) {
      float4 v = make_float4(acc[oc][0], acc[oc][1], acc[oc][2], acc[oc][3]);
      *(float4*)(ob + (size_t)oc * 252 * 252) = v;
    }
  }
}

extern "C" void kernel_launch(void* const* d_in, const int* in_sizes, int n_in,
                              void* d_out, int out_size, void* d_ws, size_t ws_size,
                              hipStream_t stream) {
  const float* x  = (const float*)d_in[0];
  const float* w3 = (const float*)d_in[1];
  const float* b3 = (const float*)d_in[2];
  const float* w4 = (const float*)d_in[3];
  const float* b4 = (const float*)d_in[4];
  const float* w6 = (const float*)d_in[5];
  const float* b6 = (const float*)d_in[6];
  float* out = (float*)d_out;

  dim3 grid(4, 16, 128);   // x-tiles, y-tiles, batch
  dim3 block(256);
  hipLaunchKernelGGL(conv_fused, grid, block, 0, stream,
                     x, w3, b3, w4, b4, w6, b6, out);
}

// Round 4
// 1054.678 us; speedup vs baseline: 1.6890x; 1.6890x over previous
//
#include <hip/hip_runtime.h>

// Fused grouped conv: x(128,6,256,256) fp32, VALID 5x5, out(128,16,252,252).
// oc 0-5 = CH3 (3 in-ch), oc 6-14 = CH4 (4 in-ch), oc 15 = CH6 (6 in-ch).
//
// Split across TWO kernels by output channel to halve the accumulator set:
//   conv_half<0>: oc 0..7   (26 weight-rows)  acc[8][4]
//   conv_half<1>: oc 8..15  (34 weight-rows)  acc[8][4]
// Per channel c, the 5x8 input window is loaded into registers ONCE, then
// each consumer row (25 contiguous scalar weights -> SGPRs) drives 100 FMAs
// whose operands are all in registers: near-pure v_fma_f32 stream.
//
// Per-half consumer tables (kind: 0=w3 1=w4 2=w6; TO = local oc = oc - 8*H).
// ROUND-3 BUG (absmax 1.36): TP[1][5]/TO[1][5] dropped the oc14 (w4 g8 pos3)
// entry and shifted — oc14 got the w6 weight, oc15 got garbage. Re-derived
// every row from the verified round-2 CKIND/CG/CPOS tables; only row [1][5]
// was wrong. Fixed: TP[1][5]={3,3,3,3,3,3,5}, TO[1][5]={0,1,2,3,5,6,7}.
namespace {
constexpr int NC[2][6]    = {{4,5,5,5,4,3},{6,5,5,5,6,7}};
constexpr int TK[2][6][7] = {
  {{0,0,0,1,0,0,0},{0,0,0,1,1,0,0},{0,0,0,1,1,0,0},{0,0,0,1,1,0,0},{0,0,0,1,0,0,0},{0,0,0,0,0,0,0}},
  {{1,1,1,1,1,2,0},{1,1,1,1,2,0,0},{1,1,1,1,2,0,0},{1,1,1,1,2,0,0},{1,1,1,1,1,2,0},{1,1,1,1,1,1,2}},
};
constexpr int TG[2][6][7] = {
  {{0,4,5,0,0,0,0},{0,1,5,0,1,0,0},{0,1,2,0,1,0,0},{1,2,3,0,1,0,0},{2,3,4,1,0,0,0},{3,4,5,0,0,0,0}},
  {{3,4,5,6,8,0,0},{4,5,6,7,0,0,0},{2,5,7,8,0,0,0},{2,3,6,8,0,0,0},{2,3,4,6,7,0,0},{2,3,4,5,7,8,0}},
};
constexpr int TP[2][6][7] = {
  {{0,0,0,0,0,0,0},{1,0,1,1,0,0,0},{2,1,0,2,1,0,0},{2,1,0,3,2,0,0},{2,1,1,3,0,0,0},{2,2,2,0,0,0,0}},
  {{0,0,0,0,0,0,0},{1,1,1,0,1,0,0},{0,2,1,1,2,0,0},{1,1,2,2,3,0,0},{2,2,2,3,2,4,0},{3,3,3,3,3,3,5}},
};
constexpr int TO[2][6][7] = {
  {{0,4,5,6,0,0,0},{0,1,5,6,7,0,0},{0,1,2,6,7,0,0},{1,2,3,6,7,0,0},{2,3,4,7,0,0,0},{3,4,5,0,0,0,0}},
  {{1,2,3,4,6,7,0},{2,3,4,5,7,0,0},{0,3,5,6,7,0,0},{0,1,4,6,7,0,0},{0,1,2,4,5,7,0},{0,1,2,3,5,6,7}},
};
} // namespace

#define TW 64
#define TH 16
#define IW 68   // TW+4
#define IH 20   // TH+4
#define LDS_CH (IH*IW)  // 1360 floats per channel

// Empirical allocator rule on this toolchain (rounds 0-2): declared min-waves n
// -> VGPR alloc at the 2n-waves/EU budget (4->64, 2->128, 1->208).
// Live set here ~100 (acc 32 + window 40 + temps), so (256,2) -> <=128, no
// spill, 4 waves/SIMD.
template<int H>
__global__ __launch_bounds__(256, 2)
void conv_half(const float* __restrict__ x,
               const float* __restrict__ w3, const float* __restrict__ b3,
               const float* __restrict__ w4, const float* __restrict__ b4,
               const float* __restrict__ w6, const float* __restrict__ b6,
               float* __restrict__ out)
{
  __shared__ __align__(16) float smem[6 * LDS_CH];
  const int tid = threadIdx.x;
  const int bx = blockIdx.x;       // 0..3   x-tiles
  const int by = blockIdx.y;       // 0..15  y-tiles
  const int b  = blockIdx.z;       // batch
  const int x0 = bx * TW;
  const int y0 = by * TH;

  // ---- stage 6 x 20 x 68 input tile into LDS (float4, zero-fill OOB) ----
  const float* xb = x + (size_t)b * 6 * 256 * 256;
  for (int i = tid; i < 6 * IH * 17; i += 256) {
    int row = i / 17;            // 0..119
    int v   = i - row * 17;      // 0..16 (float4 index within row)
    int c   = row / IH;
    int y   = row - c * IH;
    int gy  = y0 + y;
    int gx  = x0 + v * 4;
    float4 val = make_float4(0.f, 0.f, 0.f, 0.f);
    if (gy < 256 && gx < 256)
      val = *(const float4*)(xb + ((size_t)c * 256 + gy) * 256 + gx);
    *(float4*)(&smem[c * LDS_CH + y * IW + v * 4]) = val;
  }
  __syncthreads();

  const int tx = (tid & 15) * 4;   // output col within tile: 0,4,...,60
  const int ty = tid >> 4;         // output row within tile: 0..15

  // ---- accumulators: 8 local oc x 4 px, init with bias ----
  float acc[8][4];
  #pragma unroll
  for (int l = 0; l < 8; ++l) {
    const int oc = H * 8 + l;
    float bv = (oc < 6) ? b3[oc] : (oc < 15 ? b4[oc - 6] : b6[0]);
    #pragma unroll
    for (int p = 0; p < 4; ++p) acc[l][p] = bv;
  }

  // ---- main loop: per channel, window -> regs once, then consumer rows ----
  #pragma unroll
  for (int c = 0; c < 6; ++c) {
    float win[5][8];
    #pragma unroll
    for (int ky = 0; ky < 5; ++ky) {
      const float* rp = &smem[c * LDS_CH + (ty + ky) * IW + tx];
      float4 ra = *(const float4*)rp;
      float4 rb = *(const float4*)(rp + 4);
      win[ky][0] = ra.x; win[ky][1] = ra.y; win[ky][2] = ra.z; win[ky][3] = ra.w;
      win[ky][4] = rb.x; win[ky][5] = rb.y; win[ky][6] = rb.z; win[ky][7] = rb.w;
    }
    #pragma unroll
    for (int e = 0; e < 7; ++e) {
      if (e < NC[H][c]) {
        const int kind = TK[H][c][e];
        const int g    = TG[H][c][e];
        const int pos  = TP[H][c][e];
        const int l    = TO[H][c][e];
        const float* wr = (kind == 0) ? (w3 + (g * 3 + pos) * 25)
                        : (kind == 1) ? (w4 + (g * 4 + pos) * 25)
                                      : (w6 + pos * 25);
        #pragma unroll
        for (int ky = 0; ky < 5; ++ky) {
          #pragma unroll
          for (int kx = 0; kx < 5; ++kx) {
            const float wv = wr[ky * 5 + kx];
            #pragma unroll
            for (int p = 0; p < 4; ++p)
              acc[l][p] = fmaf(win[ky][kx + p], wv, acc[l][p]);
          }
        }
      }
    }
  }

  // ---- store: float4 per oc, guarded (252 % 4 == 0 so vec4 guard is exact) ----
  const int oy = y0 + ty;
  const int ox = x0 + tx;
  if (oy < 252 && ox < 252) {
    float* ob = out + (((size_t)b * 16 + H * 8) * 252 + oy) * 252 + ox;
    #pragma unroll
    for (int l = 0; l < 8; ++l) {
      float4 v = make_float4(acc[l][0], acc[l][1], acc[l][2], acc[l][3]);
      *(float4*)(ob + (size_t)l * 252 * 252) = v;
    }
  }
}

extern "C" void kernel_launch(void* const* d_in, const int* in_sizes, int n_in,
                              void* d_out, int out_size, void* d_ws, size_t ws_size,
                              hipStream_t stream) {
  const float* x  = (const float*)d_in[0];
  const float* w3 = (const float*)d_in[1];
  const float* b3 = (const float*)d_in[2];
  const float* w4 = (const float*)d_in[3];
  const float* b4 = (const float*)d_in[4];
  const float* w6 = (const float*)d_in[5];
  const float* b6 = (const float*)d_in[6];
  float* out = (float*)d_out;

  dim3 grid(4, 16, 128);   // x-tiles, y-tiles, batch
  dim3 block(256);
  hipLaunchKernelGGL(conv_half<0>, grid, block, 0, stream,
                     x, w3, b3, w4, b4, w6, b6, out);
  hipLaunchKernelGGL(conv_half<1>, grid, block, 0, stream,
                     x, w3, b3, w4, b4, w6, b6, out);
}